// Round 2
// baseline (376.467 us; speedup 1.0000x reference)
//
#include <hip/hip_runtime.h>

// Problem constants
#define Cn   192      // channels = 3*D
#define Dn   64       // hidden
#define G3   192      // 3*D gates
#define HWn  16384    // H*W per batch
#define NSp  131072L  // B*H*W total spatial
#define Tn   128

typedef unsigned short u16;
typedef __attribute__((ext_vector_type(8))) short s8v;   // 8 bf16 (4 VGPRs) MFMA A/B frag
typedef __attribute__((ext_vector_type(4))) float f4v;   // MFMA C/D frag

__device__ __forceinline__ float bf2f(u16 u){
  union { unsigned int i; float f; } v; v.i = ((unsigned int)u) << 16; return v.f;
}
__device__ __forceinline__ u16 f2bf(float f){
  union { float f; unsigned int u; } v; v.f = f;
  return (u16)((v.u + 0x7FFFu + ((v.u >> 16) & 1u)) >> 16);  // RNE
}
__device__ __forceinline__ s8v load8_f32_as_bf16(const float* __restrict__ p){
  s8v r;
  #pragma unroll
  for (int i = 0; i < 8; i++) r[i] = (short)f2bf(p[i]);
  return r;
}
// fast transcendentals
__device__ __forceinline__ float ex2f(float x){
#if __has_builtin(__builtin_amdgcn_exp2f)
  return __builtin_amdgcn_exp2f(x);
#else
  float r; asm("v_exp_f32 %0, %1" : "=v"(r) : "v"(x)); return r;
#endif
}
__device__ __forceinline__ float rcpa(float x){
#if __has_builtin(__builtin_amdgcn_rcpf)
  return __builtin_amdgcn_rcpf(x);
#else
  float r; asm("v_rcp_f32 %0, %1" : "=v"(r) : "v"(x)); return r;
#endif
}

// gate-group scale folded into weights: r,z: -log2(e)  (sigmoid(x)=rcp(1+exp2(-log2e*x)))
//                                       n:   -2log2(e) (tanh(y)=2*rcp(1+exp2(-2log2e*y))-1)
#define SC_RZ (-1.4426950408889634f)
#define SC_N  (-2.8853900817779268f)

// ---------------------------------------------------------------------------
// Kernel 0: W_comb = W_ih @ Wi (bf16, gate-scaled); b_comb = W_ih@bi + b_ih
// (+ b_hh for r,z gates only — n's b_hh sits inside r*(.) and cannot fold), scaled.
// ---------------------------------------------------------------------------
__global__ __launch_bounds__(256) void k_wcomb(const float* __restrict__ Wi, const float* __restrict__ bi,
                                               const float* __restrict__ W_ih, const float* __restrict__ b_ih,
                                               const float* __restrict__ b_hh,
                                               u16* __restrict__ wcomb, float* __restrict__ bcomb){
  if (blockIdx.x < 144) {
    int idx = blockIdx.x * 256 + threadIdx.x;   // 36864 = 192*192
    int g = idx / 192, c = idx - g * 192;
    float acc = 0.f;
    #pragma unroll 8
    for (int d = 0; d < 64; d++)
      acc += W_ih[g * 64 + d] * Wi[d * 192 + c];
    float sc = (g >= 128) ? SC_N : SC_RZ;
    wcomb[g * 192 + c] = f2bf(sc * acc);
  } else if (threadIdx.x < 192) {
    int g = threadIdx.x;
    float acc = b_ih[g];
    for (int d = 0; d < 64; d++)
      acc += W_ih[g * 64 + d] * bi[d];
    if (g < 128) acc += b_hh[g];          // fold r,z hidden-bias into the x-gate stream
    float sc = (g >= 128) ? SC_N : SC_RZ;
    bcomb[g] = sc * acc;
  }
}

// ---------------------------------------------------------------------------
// Kernel 1: G[s][g] = b_comb[g] + sum_c x[c][s] * W_comb[g][c]   (bf16 out, pre-scaled)
// ---------------------------------------------------------------------------
__global__ __launch_bounds__(256) void k_gates(const float* __restrict__ x, const u16* __restrict__ wcomb,
                                               const float* __restrict__ bcomb, u16* __restrict__ G){
  __shared__ u16 xT[64][200];
  const int tid = threadIdx.x;
  const int wave = tid >> 6, lane = tid & 63;
  const int col = lane & 15, kq = lane >> 4;
  const long s0 = (long)blockIdx.x * 64;
  const int b   = (int)(s0 >> 14);
  const int hw0 = (int)(s0 & 16383);

  s8v bfrag[3][6];
  #pragma unroll
  for (int j = 0; j < 3; j++) {
    int g = wave * 48 + j * 16 + col;
    #pragma unroll
    for (int kc = 0; kc < 6; kc++)
      bfrag[j][kc] = *(const s8v*)(wcomb + g * 192 + kc * 32 + kq * 8);
  }

  for (int idx = tid; idx < 192 * 16; idx += 256) {
    int c  = idx >> 4;
    int s4 = (idx & 15) * 4;
    float4 v = *(const float4*)(x + (long)(b * 192 + c) * HWn + hw0 + s4);
    xT[s4 + 0][c] = f2bf(v.x); xT[s4 + 1][c] = f2bf(v.y);
    xT[s4 + 2][c] = f2bf(v.z); xT[s4 + 3][c] = f2bf(v.w);
  }
  __syncthreads();

  f4v acc[4][3];
  #pragma unroll
  for (int m = 0; m < 4; m++)
    #pragma unroll
    for (int j = 0; j < 3; j++) acc[m][j] = (f4v){0.f, 0.f, 0.f, 0.f};

  #pragma unroll
  for (int kc = 0; kc < 6; kc++) {
    #pragma unroll
    for (int m = 0; m < 4; m++) {
      s8v a = *(const s8v*)(&xT[m * 16 + col][kc * 32 + kq * 8]);
      #pragma unroll
      for (int j = 0; j < 3; j++)
        acc[m][j] = __builtin_amdgcn_mfma_f32_16x16x32_bf16(a, bfrag[j][kc], acc[m][j], 0, 0, 0);
    }
  }

  #pragma unroll
  for (int j = 0; j < 3; j++) {
    int g = wave * 48 + j * 16 + col;
    float bias = bcomb[g];
    #pragma unroll
    for (int m = 0; m < 4; m++) {
      #pragma unroll
      for (int r = 0; r < 4; r++) {
        long srow = s0 + m * 16 + kq * 4 + r;
        G[srow * 192 + g] = f2bf(acc[m][j][r] + bias);
      }
    }
  }
}

// ---------------------------------------------------------------------------
// Kernel 2: directional GRU scans — SINGLE-WAVE, fully register-local.
// One wave (64 threads) owns 16 sequences x all 64 d. HG^T = W_hh @ h^T via
// 12 m-tiles x 2 k-chunks = 24 MFMAs/step. With the sigma k-permutation
// (slot (kc,half,kq,i) <-> d = kc*32+half*16+4kq+i), lane (col,kq)'s MFMA
// outputs (gates 16j+4kq+r, seq col) are EXACTLY the h values its own
// B-fragment needs next step -> no LDS, no barriers, no vmcnt drains.
// G prefetch (t+1) gets a full step (~1000 cy) of latency slack.
// ---------------------------------------------------------------------------
__global__ __launch_bounds__(64, 1) void k_scan(const u16* __restrict__ G, const float* __restrict__ W_hh,
                                                const float* __restrict__ b_hh, u16* __restrict__ Hall){
  const int lane = threadIdx.x & 63;
  const int col = lane & 15, kq = lane >> 4;
  const int dir  = blockIdx.x >> 6;   // 0:right 1:down 2:left 3:up
  const int sblk = blockIdx.x & 63;

  // A-frags: 12 m-tiles (gates 16j..16j+15), k-slots sigma-permuted, gate-scaled
  s8v afrag[12][2];
  #pragma unroll
  for (int j = 0; j < 12; j++) {
    float sc = (j >= 8) ? SC_N : SC_RZ;
    const float* wr = W_hh + (j * 16 + col) * 64;
    #pragma unroll
    for (int kc = 0; kc < 2; kc++) {
      s8v f;
      #pragma unroll
      for (int i = 0; i < 4; i++) f[i]     = (short)f2bf(sc * wr[kc * 32 +      4 * kq + i]);
      #pragma unroll
      for (int i = 0; i < 4; i++) f[4 + i] = (short)f2bf(sc * wr[kc * 32 + 16 + 4 * kq + i]);
      afrag[j][kc] = f;
    }
  }
  // n-gate hidden bias (must live in accumulator init, not in G)
  f4v biasn[4];
  #pragma unroll
  for (int jp = 0; jp < 4; jp++) {
    const float* bb = b_hh + 128 + jp * 16 + 4 * kq;
    biasn[jp] = (f4v){SC_N * bb[0], SC_N * bb[1], SC_N * bb[2], SC_N * bb[3]};
  }

  const int seq = sblk * 16 + col;             // 0..1023
  const int b = seq >> 7, a = seq & 127;
  long base; int stride;
  if ((dir & 1) == 0) { base = ((long)(b * 128 + a)) * 128; stride = 1;   } // scan over w
  else                { base = (long)b * 16384 + a;         stride = 128; } // scan over h
  const int rev = dir >> 1;
  const long pd = rev ? -(long)stride : (long)stride;
  u16* __restrict__ Hs = Hall + (long)dir * (NSp * 64);

  const long pos0 = base + (long)(rev ? 127 : 0) * stride;
  const u16* gq = G  + pos0 * 192 + 4 * kq;    // lane base; g3/jp offsets fold to immediates
  u16*       hq = Hs + pos0 * 64  + 4 * kq;

  // xg for t=0 (pre-scaled, r/z b_hh already folded in)
  uint2 xc[12];
  #pragma unroll
  for (int g3 = 0; g3 < 3; g3++)
    #pragma unroll
    for (int jp = 0; jp < 4; jp++)
      xc[g3 * 4 + jp] = *(const uint2*)(gq + g3 * 64 + jp * 16);

  float hold[16];
  #pragma unroll
  for (int i = 0; i < 16; i++) hold[i] = 0.f;
  union BW { unsigned int u[4]; s8v v; } ba, bb2;    // h bf16, sigma slot order
  #pragma unroll
  for (int i = 0; i < 4; i++) { ba.u[i] = 0u; bb2.u[i] = 0u; }

  for (int t = 0; t < 128; t++) {
    // prefetch xg for t+1 — consumed next iteration, ~full step of slack
    uint2 nx[12];
    if (t < 127) {
      gq += pd * 192;
      #pragma unroll
      for (int g3 = 0; g3 < 3; g3++)
        #pragma unroll
        for (int jp = 0; jp < 4; jp++)
          nx[g3 * 4 + jp] = *(const uint2*)(gq + g3 * 64 + jp * 16);
    }

    // ---- 24 MFMAs, grouped so gate jp=0 unblocks after 6 ----
    f4v acc[12];
    #pragma unroll
    for (int j = 0; j < 8; j++) acc[j] = (f4v){0.f, 0.f, 0.f, 0.f};
    #pragma unroll
    for (int jp = 0; jp < 4; jp++) acc[8 + jp] = biasn[jp];
    #pragma unroll
    for (int jp = 0; jp < 4; jp++) {
      acc[jp]     = __builtin_amdgcn_mfma_f32_16x16x32_bf16(afrag[jp][0],     ba.v,  acc[jp],     0, 0, 0);
      acc[4 + jp] = __builtin_amdgcn_mfma_f32_16x16x32_bf16(afrag[4 + jp][0], ba.v,  acc[4 + jp], 0, 0, 0);
      acc[8 + jp] = __builtin_amdgcn_mfma_f32_16x16x32_bf16(afrag[8 + jp][0], ba.v,  acc[8 + jp], 0, 0, 0);
      acc[jp]     = __builtin_amdgcn_mfma_f32_16x16x32_bf16(afrag[jp][1],     bb2.v, acc[jp],     0, 0, 0);
      acc[4 + jp] = __builtin_amdgcn_mfma_f32_16x16x32_bf16(afrag[4 + jp][1], bb2.v, acc[4 + jp], 0, 0, 0);
      acc[8 + jp] = __builtin_amdgcn_mfma_f32_16x16x32_bf16(afrag[8 + jp][1], bb2.v, acc[8 + jp], 0, 0, 0);
    }

    // ---- gate phase: everything lane-local ----
    #pragma unroll
    for (int jp = 0; jp < 4; jp++) {
      const u16* pxr = (const u16*)&xc[jp];
      const u16* pxz = (const u16*)&xc[4 + jp];
      const u16* pxn = (const u16*)&xc[8 + jp];
      float hh[4];
      #pragma unroll
      for (int r = 0; r < 4; r++) {
        float rr = rcpa(1.f + ex2f(bf2f(pxr[r]) + acc[jp][r]));
        float zz = rcpa(1.f + ex2f(bf2f(pxz[r]) + acc[4 + jp][r]));
        float nn = 2.f * rcpa(1.f + ex2f(bf2f(pxn[r]) + rr * acc[8 + jp][r])) - 1.f;
        float h  = nn + zz * (hold[jp * 4 + r] - nn);
        hold[jp * 4 + r] = h;
        hh[r] = h;
      }
      unsigned int w0, w1;
      asm("v_cvt_pk_bf16_f32 %0, %1, %2" : "=v"(w0) : "v"(hh[0]), "v"(hh[1]));   // RNE pack
      asm("v_cvt_pk_bf16_f32 %0, %1, %2" : "=v"(w1) : "v"(hh[2]), "v"(hh[3]));
      if (jp == 0)      { ba.u[0]  = w0; ba.u[1]  = w1; }
      else if (jp == 1) { ba.u[2]  = w0; ba.u[3]  = w1; }
      else if (jp == 2) { bb2.u[0] = w0; bb2.u[1] = w1; }
      else              { bb2.u[2] = w0; bb2.u[3] = w1; }
      uint2 wv; wv.x = w0; wv.y = w1;
      *(uint2*)(hq + jp * 16) = wv;                 // stream h out (never waited on)
    }
    hq += pd * 64;
    if (t < 127) {
      #pragma unroll
      for (int i = 0; i < 12; i++) xc[i] = nx[i];
    }
  }
}

// ---------------------------------------------------------------------------
// Kernel 3: out[b,c,h,w] = bo[c] + Wo[c,:] . (sum_dirs h)/4   (fp32 out)
// ---------------------------------------------------------------------------
__global__ __launch_bounds__(256) void k_out(const u16* __restrict__ Hall, const float* __restrict__ Wo,
                                             const float* __restrict__ bo, float* __restrict__ out){
  __shared__ u16 hs4[64][72];
  const int tid = threadIdx.x;
  const int wave = tid >> 6, lane = tid & 63;
  const int col = lane & 15, kq = lane >> 4;
  const long s0 = (long)blockIdx.x * 64;
  const int b   = (int)(s0 >> 14);
  const int hw0 = (int)(s0 & 16383);

  s8v bfrag[3][2]; f4v biasf[3];
  #pragma unroll
  for (int j = 0; j < 3; j++) {
    int g = wave * 48 + j * 16 + col;
    bfrag[j][0] = load8_f32_as_bf16(Wo + g * 64 + kq * 8);
    bfrag[j][1] = load8_f32_as_bf16(Wo + g * 64 + 32 + kq * 8);
    float bb = bo[g];
    biasf[j] = (f4v){bb, bb, bb, bb};
  }

  for (int idx = tid; idx < 64 * 16; idx += 256) {
    int sl = idx >> 4;
    int d4 = (idx & 15) * 4;
    long p = (s0 + sl) * 64 + d4;
    float a0 = 0.f, a1 = 0.f, a2 = 0.f, a3 = 0.f;
    #pragma unroll
    for (int dd = 0; dd < 4; dd++) {
      uint2 v = *(const uint2*)(Hall + dd * (NSp * 64) + p);
      u16* pv = (u16*)&v;
      a0 += bf2f(pv[0]); a1 += bf2f(pv[1]); a2 += bf2f(pv[2]); a3 += bf2f(pv[3]);
    }
    ushort4 o;
    o.x = f2bf(0.25f * a0); o.y = f2bf(0.25f * a1);
    o.z = f2bf(0.25f * a2); o.w = f2bf(0.25f * a3);
    *(ushort4*)(&hs4[sl][d4]) = o;
  }
  __syncthreads();

  f4v acc[4][3];
  #pragma unroll
  for (int m = 0; m < 4; m++)
    #pragma unroll
    for (int j = 0; j < 3; j++) acc[m][j] = biasf[j];

  #pragma unroll
  for (int kc = 0; kc < 2; kc++) {
    #pragma unroll
    for (int m = 0; m < 4; m++) {
      s8v a = *(const s8v*)(&hs4[m * 16 + col][kc * 32 + kq * 8]);
      #pragma unroll
      for (int j = 0; j < 3; j++)
        acc[m][j] = __builtin_amdgcn_mfma_f32_16x16x32_bf16(a, bfrag[j][kc], acc[m][j], 0, 0, 0);
    }
  }

  #pragma unroll
  for (int j = 0; j < 3; j++) {
    int g = wave * 48 + j * 16 + col;
    #pragma unroll
    for (int m = 0; m < 4; m++) {
      float4 v;
      v.x = acc[m][j][0]; v.y = acc[m][j][1];
      v.z = acc[m][j][2]; v.w = acc[m][j][3];
      long addr = ((long)(b * 192 + g) << 14) + hw0 + m * 16 + kq * 4;
      *(float4*)(out + addr) = v;
    }
  }
}

// ---------------------------------------------------------------------------
extern "C" void kernel_launch(void* const* d_in, const int* in_sizes, int n_in,
                              void* d_out, int out_size, void* d_ws, size_t ws_size,
                              hipStream_t stream){
  const float* x    = (const float*)d_in[0];
  const float* Wi   = (const float*)d_in[1];
  const float* bi   = (const float*)d_in[2];
  const float* W_ih = (const float*)d_in[3];
  const float* W_hh = (const float*)d_in[4];
  const float* b_ih = (const float*)d_in[5];
  const float* b_hh = (const float*)d_in[6];
  const float* Wo   = (const float*)d_in[7];
  const float* bo   = (const float*)d_in[8];

  char* ws = (char*)d_ws;
  u16*   wcomb = (u16*)(ws);                       // 192*192 bf16        = 73728 B
  float* bcomb = (float*)(ws + 73728);             // 192 fp32            = 768 B
  u16*   G     = (u16*)(ws + 74496);               // 131072*192 bf16     = 50331648 B
  u16*   Hall  = (u16*)(ws + 50406144);            // 4*131072*64 bf16    = 67108864 B
                                                   // total               = 117515008 B

  k_wcomb<<<145,  256, 0, stream>>>(Wi, bi, W_ih, b_ih, b_hh, wcomb, bcomb);
  k_gates<<<2048, 256, 0, stream>>>(x, wcomb, bcomb, G);
  k_scan <<<256,   64, 0, stream>>>(G, W_hh, b_hh, Hall);
  k_out  <<<2048, 256, 0, stream>>>(Hall, Wo, bo, (float*)d_out);
}

// Round 3
// 306.085 us; speedup vs baseline: 1.2299x; 1.2299x over previous
//
#include <hip/hip_runtime.h>

// Problem constants
#define Cn   192      // channels = 3*D
#define Dn   64       // hidden
#define G3   192      // 3*D gates
#define HWn  16384    // H*W per batch
#define NSp  131072L  // B*H*W total spatial
#define Tn   128

typedef unsigned short u16;
typedef __attribute__((ext_vector_type(8))) short s8v;   // 8 bf16 (4 VGPRs) MFMA A/B frag
typedef __attribute__((ext_vector_type(4))) float f4v;   // MFMA C/D frag

__device__ __forceinline__ float bf2f(u16 u){
  union { unsigned int i; float f; } v; v.i = ((unsigned int)u) << 16; return v.f;
}
__device__ __forceinline__ u16 f2bf(float f){
  union { float f; unsigned int u; } v; v.f = f;
  return (u16)((v.u + 0x7FFFu + ((v.u >> 16) & 1u)) >> 16);  // RNE
}
__device__ __forceinline__ s8v load8_f32_as_bf16(const float* __restrict__ p){
  s8v r;
  #pragma unroll
  for (int i = 0; i < 8; i++) r[i] = (short)f2bf(p[i]);
  return r;
}
// fast transcendentals
__device__ __forceinline__ float ex2f(float x){
#if __has_builtin(__builtin_amdgcn_exp2f)
  return __builtin_amdgcn_exp2f(x);
#else
  float r; asm("v_exp_f32 %0, %1" : "=v"(r) : "v"(x)); return r;
#endif
}
__device__ __forceinline__ float rcpa(float x){
#if __has_builtin(__builtin_amdgcn_rcpf)
  return __builtin_amdgcn_rcpf(x);
#else
  float r; asm("v_rcp_f32 %0, %1" : "=v"(r) : "v"(x)); return r;
#endif
}

// gate-group scale folded into weights: r,z: -log2(e)  (sigmoid(x)=rcp(1+exp2(-log2e*x)))
//                                       n:   -2log2(e) (tanh(y)=2*rcp(1+exp2(-2log2e*y))-1)
#define SC_RZ (-1.4426950408889634f)
#define SC_N  (-2.8853900817779268f)

// ---------------------------------------------------------------------------
// Kernel 0: W_comb = W_ih @ Wi (bf16, gate-scaled); b_comb = W_ih@bi + b_ih
// (+ b_hh for r,z gates only — n's b_hh sits inside r*(.) and cannot fold), scaled.
// ---------------------------------------------------------------------------
__global__ __launch_bounds__(256) void k_wcomb(const float* __restrict__ Wi, const float* __restrict__ bi,
                                               const float* __restrict__ W_ih, const float* __restrict__ b_ih,
                                               const float* __restrict__ b_hh,
                                               u16* __restrict__ wcomb, float* __restrict__ bcomb){
  if (blockIdx.x < 144) {
    int idx = blockIdx.x * 256 + threadIdx.x;   // 36864 = 192*192
    int g = idx / 192, c = idx - g * 192;
    float acc = 0.f;
    #pragma unroll 8
    for (int d = 0; d < 64; d++)
      acc += W_ih[g * 64 + d] * Wi[d * 192 + c];
    float sc = (g >= 128) ? SC_N : SC_RZ;
    wcomb[g * 192 + c] = f2bf(sc * acc);
  } else if (threadIdx.x < 192) {
    int g = threadIdx.x;
    float acc = b_ih[g];
    for (int d = 0; d < 64; d++)
      acc += W_ih[g * 64 + d] * bi[d];
    if (g < 128) acc += b_hh[g];          // fold r,z hidden-bias into the x-gate stream
    float sc = (g >= 128) ? SC_N : SC_RZ;
    bcomb[g] = sc * acc;
  }
}

// ---------------------------------------------------------------------------
// Kernel 1: G[s][g] = b_comb[g] + sum_c x[c][s] * W_comb[g][c]   (bf16 out, pre-scaled)
// ---------------------------------------------------------------------------
__global__ __launch_bounds__(256) void k_gates(const float* __restrict__ x, const u16* __restrict__ wcomb,
                                               const float* __restrict__ bcomb, u16* __restrict__ G){
  __shared__ u16 xT[64][200];
  const int tid = threadIdx.x;
  const int wave = tid >> 6, lane = tid & 63;
  const int col = lane & 15, kq = lane >> 4;
  const long s0 = (long)blockIdx.x * 64;
  const int b   = (int)(s0 >> 14);
  const int hw0 = (int)(s0 & 16383);

  s8v bfrag[3][6];
  #pragma unroll
  for (int j = 0; j < 3; j++) {
    int g = wave * 48 + j * 16 + col;
    #pragma unroll
    for (int kc = 0; kc < 6; kc++)
      bfrag[j][kc] = *(const s8v*)(wcomb + g * 192 + kc * 32 + kq * 8);
  }

  for (int idx = tid; idx < 192 * 16; idx += 256) {
    int c  = idx >> 4;
    int s4 = (idx & 15) * 4;
    float4 v = *(const float4*)(x + (long)(b * 192 + c) * HWn + hw0 + s4);
    xT[s4 + 0][c] = f2bf(v.x); xT[s4 + 1][c] = f2bf(v.y);
    xT[s4 + 2][c] = f2bf(v.z); xT[s4 + 3][c] = f2bf(v.w);
  }
  __syncthreads();

  f4v acc[4][3];
  #pragma unroll
  for (int m = 0; m < 4; m++)
    #pragma unroll
    for (int j = 0; j < 3; j++) acc[m][j] = (f4v){0.f, 0.f, 0.f, 0.f};

  #pragma unroll
  for (int kc = 0; kc < 6; kc++) {
    #pragma unroll
    for (int m = 0; m < 4; m++) {
      s8v a = *(const s8v*)(&xT[m * 16 + col][kc * 32 + kq * 8]);
      #pragma unroll
      for (int j = 0; j < 3; j++)
        acc[m][j] = __builtin_amdgcn_mfma_f32_16x16x32_bf16(a, bfrag[j][kc], acc[m][j], 0, 0, 0);
    }
  }

  #pragma unroll
  for (int j = 0; j < 3; j++) {
    int g = wave * 48 + j * 16 + col;
    float bias = bcomb[g];
    #pragma unroll
    for (int m = 0; m < 4; m++) {
      #pragma unroll
      for (int r = 0; r < 4; r++) {
        long srow = s0 + m * 16 + kq * 4 + r;
        G[srow * 192 + g] = f2bf(acc[m][j][r] + bias);
      }
    }
  }
}

// ---------------------------------------------------------------------------
// Kernel 2: directional GRU scans — 4-wave d-split (full machine: 1024 waves)
// + register-local sigma layout + double-buffered 2KB h-exchange in LDS.
// Barrier is RAW s_barrier with lgkmcnt(0)-only drain: the G prefetch
// (issued 2 steps ahead) stays in flight across barriers (counted vmcnt at
// consume, never 0) — removes the ~1200cy/step __syncthreads vmcnt drain
// that bounded round 1.
// Race audit: step t reads ha[p] (own lgkm drained pre-barrier), writes
// ha[p^1]; ha[p] is rewritten only in step t+1 after barrier t -> safe.
// ---------------------------------------------------------------------------
__global__ __launch_bounds__(256) void k_scan(const u16* __restrict__ G, const float* __restrict__ W_hh,
                                              const float* __restrict__ b_hh, u16* __restrict__ Hall){
  __shared__ u16 ha[2][16][72];   // [buf][seq][d], row 144 B
  const int tid = threadIdx.x;
  const int w = tid >> 6, lane = tid & 63;
  const int col = lane & 15, kq = lane >> 4;
  const int dir  = blockIdx.x >> 6;   // 0:right 1:down 2:left 3:up
  const int sblk = blockIdx.x & 63;
  const int doff = 16 * w + 4 * kq;   // this lane's 4 d values: doff..doff+3

  // A-frags: W_hh rows g = g3*64 + 16w + m, sigma-permuted k slots, gate-scaled
  s8v afrag[3][2];
  #pragma unroll
  for (int g3 = 0; g3 < 3; g3++) {
    float sc = (g3 == 2) ? SC_N : SC_RZ;
    const float* wr = W_hh + (g3 * 64 + 16 * w + col) * 64;
    #pragma unroll
    for (int kc = 0; kc < 2; kc++) {
      s8v f;
      #pragma unroll
      for (int i = 0; i < 4; i++) f[i]     = (short)f2bf(sc * wr[kc * 32 +      4 * kq + i]);
      #pragma unroll
      for (int i = 0; i < 4; i++) f[4 + i] = (short)f2bf(sc * wr[kc * 32 + 16 + 4 * kq + i]);
      afrag[g3][kc] = f;
    }
  }
  // n-gate hidden bias lives in accumulator init (r,z b_hh folded into G)
  f4v biasn;
  {
    const float* bb = b_hh + 128 + doff;
    biasn = (f4v){SC_N * bb[0], SC_N * bb[1], SC_N * bb[2], SC_N * bb[3]};
  }

  const int seq = sblk * 16 + col;             // 0..1023
  const int b = seq >> 7, a = seq & 127;
  long base; int stride;
  if ((dir & 1) == 0) { base = ((long)(b * 128 + a)) * 128; stride = 1;   } // scan over w
  else                { base = (long)b * 16384 + a;         stride = 128; } // scan over h
  const int rev = dir >> 1;
  const long pd = rev ? -(long)stride : (long)stride;
  u16* __restrict__ Hs = Hall + (long)dir * (NSp * 64);
  const long pos0 = base + (long)(rev ? 127 : 0) * stride;
  const u16* gq = G  + pos0 * 192 + doff;
  u16*       hq = Hs + pos0 * 64  + doff;

  for (int i = tid; i < 2 * 16 * 72; i += 256) ((u16*)ha)[i] = 0;   // h0 = 0

  float hold[4] = {0.f, 0.f, 0.f, 0.f};

  // depth-2 G prefetch: t=0 and t=1 in flight before the loop
  uint2 xr0, xz0, xn0, xr1, xz1, xn1;
  xr0 = *(const uint2*)(gq); xz0 = *(const uint2*)(gq + 64); xn0 = *(const uint2*)(gq + 128);
  gq += pd * 192;
  xr1 = *(const uint2*)(gq); xz1 = *(const uint2*)(gq + 64); xn1 = *(const uint2*)(gq + 128);
  __syncthreads();   // one full drain, before the loop only

  int p = 0;
  for (int t = 0; t < 128; t++) {
    // issue prefetch for t+2 (~2 steps of latency slack)
    uint2 nxr, nxz, nxn;
    if (t < 126) {
      gq += pd * 192;
      nxr = *(const uint2*)(gq); nxz = *(const uint2*)(gq + 64); nxn = *(const uint2*)(gq + 128);
    }

    // B-frags (n=col=seq) from ha[p], sigma slot order
    union BW { ushort4 q[2]; s8v v; } u0, u1;
    u0.q[0] = *(const ushort4*)(&ha[p][col][ 0 + 4 * kq]);
    u0.q[1] = *(const ushort4*)(&ha[p][col][16 + 4 * kq]);
    u1.q[0] = *(const ushort4*)(&ha[p][col][32 + 4 * kq]);
    u1.q[1] = *(const ushort4*)(&ha[p][col][48 + 4 * kq]);

    f4v acc0 = (f4v){0.f, 0.f, 0.f, 0.f};
    f4v acc1 = (f4v){0.f, 0.f, 0.f, 0.f};
    f4v acc2 = biasn;
    acc0 = __builtin_amdgcn_mfma_f32_16x16x32_bf16(afrag[0][0], u0.v, acc0, 0, 0, 0);
    acc1 = __builtin_amdgcn_mfma_f32_16x16x32_bf16(afrag[1][0], u0.v, acc1, 0, 0, 0);
    acc2 = __builtin_amdgcn_mfma_f32_16x16x32_bf16(afrag[2][0], u0.v, acc2, 0, 0, 0);
    acc0 = __builtin_amdgcn_mfma_f32_16x16x32_bf16(afrag[0][1], u1.v, acc0, 0, 0, 0);
    acc1 = __builtin_amdgcn_mfma_f32_16x16x32_bf16(afrag[1][1], u1.v, acc1, 0, 0, 0);
    acc2 = __builtin_amdgcn_mfma_f32_16x16x32_bf16(afrag[2][1], u1.v, acc2, 0, 0, 0);

    // gate phase — lane-local (gates g3*64 + doff + r, seq = col)
    const u16* pxr = (const u16*)&xr0;
    const u16* pxz = (const u16*)&xz0;
    const u16* pxn = (const u16*)&xn0;
    float hh[4];
    #pragma unroll
    for (int r = 0; r < 4; r++) {
      float rr = rcpa(1.f + ex2f(bf2f(pxr[r]) + acc0[r]));
      float zz = rcpa(1.f + ex2f(bf2f(pxz[r]) + acc1[r]));
      float nn = 2.f * rcpa(1.f + ex2f(bf2f(pxn[r]) + rr * acc2[r])) - 1.f;
      float h  = nn + zz * (hold[r] - nn);
      hold[r] = h; hh[r] = h;
    }
    unsigned int w0, w1;
    asm("v_cvt_pk_bf16_f32 %0, %1, %2" : "=v"(w0) : "v"(hh[0]), "v"(hh[1]));   // RNE pack
    asm("v_cvt_pk_bf16_f32 %0, %1, %2" : "=v"(w1) : "v"(hh[2]), "v"(hh[3]));
    uint2 wv; wv.x = w0; wv.y = w1;
    *(uint2*)(&ha[p ^ 1][col][doff]) = wv;   // h for next step (other buffer)
    *(uint2*)(hq) = wv;                      // stream h out (never waited on)
    hq += pd * 64;

    // rotate prefetch pipeline
    xr0 = xr1; xz0 = xz1; xn0 = xn1;
    if (t < 126) { xr1 = nxr; xz1 = nxz; xn1 = nxn; }

    // raw barrier: drain LDS only; global loads/stores stay in flight
    asm volatile("s_waitcnt lgkmcnt(0)" ::: "memory");
    __builtin_amdgcn_s_barrier();
    __builtin_amdgcn_sched_barrier(0);
    p ^= 1;
  }
}

// ---------------------------------------------------------------------------
// Kernel 3: out[b,c,h,w] = bo[c] + Wo[c,:] . (sum_dirs h)/4   (fp32 out)
// ---------------------------------------------------------------------------
__global__ __launch_bounds__(256) void k_out(const u16* __restrict__ Hall, const float* __restrict__ Wo,
                                             const float* __restrict__ bo, float* __restrict__ out){
  __shared__ u16 hs4[64][72];
  const int tid = threadIdx.x;
  const int wave = tid >> 6, lane = tid & 63;
  const int col = lane & 15, kq = lane >> 4;
  const long s0 = (long)blockIdx.x * 64;
  const int b   = (int)(s0 >> 14);
  const int hw0 = (int)(s0 & 16383);

  s8v bfrag[3][2]; f4v biasf[3];
  #pragma unroll
  for (int j = 0; j < 3; j++) {
    int g = wave * 48 + j * 16 + col;
    bfrag[j][0] = load8_f32_as_bf16(Wo + g * 64 + kq * 8);
    bfrag[j][1] = load8_f32_as_bf16(Wo + g * 64 + 32 + kq * 8);
    float bb = bo[g];
    biasf[j] = (f4v){bb, bb, bb, bb};
  }

  for (int idx = tid; idx < 64 * 16; idx += 256) {
    int sl = idx >> 4;
    int d4 = (idx & 15) * 4;
    long p = (s0 + sl) * 64 + d4;
    float a0 = 0.f, a1 = 0.f, a2 = 0.f, a3 = 0.f;
    #pragma unroll
    for (int dd = 0; dd < 4; dd++) {
      uint2 v = *(const uint2*)(Hall + dd * (NSp * 64) + p);
      u16* pv = (u16*)&v;
      a0 += bf2f(pv[0]); a1 += bf2f(pv[1]); a2 += bf2f(pv[2]); a3 += bf2f(pv[3]);
    }
    ushort4 o;
    o.x = f2bf(0.25f * a0); o.y = f2bf(0.25f * a1);
    o.z = f2bf(0.25f * a2); o.w = f2bf(0.25f * a3);
    *(ushort4*)(&hs4[sl][d4]) = o;
  }
  __syncthreads();

  f4v acc[4][3];
  #pragma unroll
  for (int m = 0; m < 4; m++)
    #pragma unroll
    for (int j = 0; j < 3; j++) acc[m][j] = biasf[j];

  #pragma unroll
  for (int kc = 0; kc < 2; kc++) {
    #pragma unroll
    for (int m = 0; m < 4; m++) {
      s8v a = *(const s8v*)(&hs4[m * 16 + col][kc * 32 + kq * 8]);
      #pragma unroll
      for (int j = 0; j < 3; j++)
        acc[m][j] = __builtin_amdgcn_mfma_f32_16x16x32_bf16(a, bfrag[j][kc], acc[m][j], 0, 0, 0);
    }
  }

  #pragma unroll
  for (int j = 0; j < 3; j++) {
    int g = wave * 48 + j * 16 + col;
    #pragma unroll
    for (int m = 0; m < 4; m++) {
      float4 v;
      v.x = acc[m][j][0]; v.y = acc[m][j][1];
      v.z = acc[m][j][2]; v.w = acc[m][j][3];
      long addr = ((long)(b * 192 + g) << 14) + hw0 + m * 16 + kq * 4;
      *(float4*)(out + addr) = v;
    }
  }
}

// ---------------------------------------------------------------------------
extern "C" void kernel_launch(void* const* d_in, const int* in_sizes, int n_in,
                              void* d_out, int out_size, void* d_ws, size_t ws_size,
                              hipStream_t stream){
  const float* x    = (const float*)d_in[0];
  const float* Wi   = (const float*)d_in[1];
  const float* bi   = (const float*)d_in[2];
  const float* W_ih = (const float*)d_in[3];
  const float* W_hh = (const float*)d_in[4];
  const float* b_ih = (const float*)d_in[5];
  const float* b_hh = (const float*)d_in[6];
  const float* Wo   = (const float*)d_in[7];
  const float* bo   = (const float*)d_in[8];

  char* ws = (char*)d_ws;
  u16*   wcomb = (u16*)(ws);                       // 192*192 bf16        = 73728 B
  float* bcomb = (float*)(ws + 73728);             // 192 fp32            = 768 B
  u16*   G     = (u16*)(ws + 74496);               // 131072*192 bf16     = 50331648 B
  u16*   Hall  = (u16*)(ws + 50406144);            // 4*131072*64 bf16    = 67108864 B
                                                   // total               = 117515008 B

  k_wcomb<<<145,  256, 0, stream>>>(Wi, bi, W_ih, b_ih, b_hh, wcomb, bcomb);
  k_gates<<<2048, 256, 0, stream>>>(x, wcomb, bcomb, G);
  k_scan <<<256,  256, 0, stream>>>(G, W_hh, b_hh, Hall);
  k_out  <<<2048, 256, 0, stream>>>(Hall, Wo, bo, (float*)d_out);
}

// Round 4
// 297.612 us; speedup vs baseline: 1.2650x; 1.0285x over previous
//
#include <hip/hip_runtime.h>

// Problem constants
#define Cn   192      // channels = 3*D
#define Dn   64       // hidden
#define G3   192      // 3*D gates
#define HWn  16384    // H*W per batch
#define NSp  131072L  // B*H*W total spatial
#define Tn   128

typedef unsigned short u16;
typedef __attribute__((ext_vector_type(8))) short s8v;   // 8 bf16 (4 VGPRs) MFMA A/B frag
typedef __attribute__((ext_vector_type(4))) float f4v;   // MFMA C/D frag

__device__ __forceinline__ float bf2f(u16 u){
  union { unsigned int i; float f; } v; v.i = ((unsigned int)u) << 16; return v.f;
}
__device__ __forceinline__ u16 f2bf(float f){
  union { float f; unsigned int u; } v; v.f = f;
  return (u16)((v.u + 0x7FFFu + ((v.u >> 16) & 1u)) >> 16);  // RNE
}
__device__ __forceinline__ s8v load8_f32_as_bf16(const float* __restrict__ p){
  s8v r;
  #pragma unroll
  for (int i = 0; i < 8; i++) r[i] = (short)f2bf(p[i]);
  return r;
}
// fast transcendentals
__device__ __forceinline__ float ex2f(float x){
#if __has_builtin(__builtin_amdgcn_exp2f)
  return __builtin_amdgcn_exp2f(x);
#else
  float r; asm("v_exp_f32 %0, %1" : "=v"(r) : "v"(x)); return r;
#endif
}
__device__ __forceinline__ float rcpa(float x){
#if __has_builtin(__builtin_amdgcn_rcpf)
  return __builtin_amdgcn_rcpf(x);
#else
  float r; asm("v_rcp_f32 %0, %1" : "=v"(r) : "v"(x)); return r;
#endif
}
__device__ __forceinline__ unsigned int pk2bf(float a, float b){
  unsigned int r; asm("v_cvt_pk_bf16_f32 %0, %1, %2" : "=v"(r) : "v"(a), "v"(b)); return r;
}

// gate-group scale folded into weights: r,z: -log2(e)  (sigmoid(x)=rcp(1+exp2(-log2e*x)))
//                                       n:   -2log2(e) (tanh(y)=2*rcp(1+exp2(-2log2e*y))-1)
#define SC_RZ (-1.4426950408889634f)
#define SC_N  (-2.8853900817779268f)

// G layout (interleaved for scan locality): per spatial s, 16 d-quads x 3 gate
// groups x 4: element offset = s*192 + dq*12 + g3*4 + r, where d = 4*dq + r.
// A lane's (r,z,n) triple for its d-quad is 24 contiguous bytes.

// ---------------------------------------------------------------------------
// Kernel 0: W_comb = W_ih @ Wi (bf16, gate-scaled); b_comb = W_ih@bi + b_ih
// (+ b_hh for r,z gates — n's b_hh sits inside r*(.) and cannot fold), scaled.
// ---------------------------------------------------------------------------
__global__ __launch_bounds__(256) void k_wcomb(const float* __restrict__ Wi, const float* __restrict__ bi,
                                               const float* __restrict__ W_ih, const float* __restrict__ b_ih,
                                               const float* __restrict__ b_hh,
                                               u16* __restrict__ wcomb, float* __restrict__ bcomb){
  if (blockIdx.x < 144) {
    int idx = blockIdx.x * 256 + threadIdx.x;   // 36864 = 192*192
    int g = idx / 192, c = idx - g * 192;
    float acc = 0.f;
    #pragma unroll 8
    for (int d = 0; d < 64; d++)
      acc += W_ih[g * 64 + d] * Wi[d * 192 + c];
    float sc = (g >= 128) ? SC_N : SC_RZ;
    wcomb[g * 192 + c] = f2bf(sc * acc);
  } else if (threadIdx.x < 192) {
    int g = threadIdx.x;
    float acc = b_ih[g];
    for (int d = 0; d < 64; d++)
      acc += W_ih[g * 64 + d] * bi[d];
    if (g < 128) acc += b_hh[g];          // fold r,z hidden-bias into the x-gate stream
    float sc = (g >= 128) ? SC_N : SC_RZ;
    bcomb[g] = sc * acc;
  }
}

// ---------------------------------------------------------------------------
// Kernel 1: G = x @ W_comb^T + b_comb  (bf16, pre-scaled, interleaved layout).
// SWAPPED operands: A = W_comb (m=gate), B = xT (n=spatial) -> lane holds 4
// consecutive gates per tile -> uint2 stores into the interleaved layout
// (vs 48 scalar 2B stores before). Bias pre-loaded into accumulators.
// ---------------------------------------------------------------------------
__global__ __launch_bounds__(256) void k_gates(const float* __restrict__ x, const u16* __restrict__ wcomb,
                                               const float* __restrict__ bcomb, u16* __restrict__ G){
  __shared__ u16 xT[64][200];                 // [spatial][channel], row 400 B
  const int tid = threadIdx.x;
  const int wave = tid >> 6, lane = tid & 63;
  const int col = lane & 15, kq = lane >> 4;
  const long s0 = (long)blockIdx.x * 64;
  const int b   = (int)(s0 >> 14);
  const int hw0 = (int)(s0 & 16383);
  const int dq  = 4 * wave + kq;              // this lane's d-quad (d = 4dq..4dq+3)

  // A-frags: gate rows g = g3*64 + 16*wave + col; k = kc*32 + kq*8 + i (standard)
  s8v afrag[3][6];
  f4v biasv[3];
  #pragma unroll
  for (int g3 = 0; g3 < 3; g3++) {
    int g = g3 * 64 + 16 * wave + col;
    #pragma unroll
    for (int kc = 0; kc < 6; kc++)
      afrag[g3][kc] = *(const s8v*)(wcomb + g * 192 + kc * 32 + kq * 8);
    biasv[g3] = *(const f4v*)(bcomb + g3 * 64 + 16 * wave + 4 * kq);
  }

  // Stage x tile transposed: float4 (4 consecutive spatial) per iter, cvt bf16
  for (int idx = tid; idx < 192 * 16; idx += 256) {
    int c  = idx >> 4;
    int s4 = (idx & 15) * 4;
    float4 v = *(const float4*)(x + (long)(b * 192 + c) * HWn + hw0 + s4);
    xT[s4 + 0][c] = f2bf(v.x); xT[s4 + 1][c] = f2bf(v.y);
    xT[s4 + 2][c] = f2bf(v.z); xT[s4 + 3][c] = f2bf(v.w);
  }
  __syncthreads();

  f4v acc[4][3];
  #pragma unroll
  for (int nt = 0; nt < 4; nt++)
    #pragma unroll
    for (int g3 = 0; g3 < 3; g3++) acc[nt][g3] = biasv[g3];

  #pragma unroll
  for (int kc = 0; kc < 6; kc++) {
    #pragma unroll
    for (int nt = 0; nt < 4; nt++) {
      s8v bx = *(const s8v*)(&xT[nt * 16 + col][kc * 32 + kq * 8]);
      #pragma unroll
      for (int g3 = 0; g3 < 3; g3++)
        acc[nt][g3] = __builtin_amdgcn_mfma_f32_16x16x32_bf16(afrag[g3][kc], bx, acc[nt][g3], 0, 0, 0);
    }
  }

  // Epilogue: D rows = gates (4kq+r within tile), col = spatial -> uint2 stores
  #pragma unroll
  for (int nt = 0; nt < 4; nt++) {
    long sRow = (s0 + nt * 16 + col) * 192 + dq * 12;
    #pragma unroll
    for (int g3 = 0; g3 < 3; g3++) {
      uint2 wv;
      wv.x = pk2bf(acc[nt][g3][0], acc[nt][g3][1]);
      wv.y = pk2bf(acc[nt][g3][2], acc[nt][g3][3]);
      *(uint2*)(G + sRow + g3 * 4) = wv;
    }
  }
}

// ---------------------------------------------------------------------------
// Kernel 2: directional GRU scans — 4-wave d-split, raw-barrier double buffer.
// Standard contiguous k-order: h B-frags are TWO ds_read_b128 (rows of
// ha[16][72] are 16B-aligned); G loads are one 24B contiguous run per lane.
// Raw s_barrier with lgkmcnt(0)-only drain; G prefetch depth 2 (never drained).
// ---------------------------------------------------------------------------
__global__ __launch_bounds__(256) void k_scan(const u16* __restrict__ G, const float* __restrict__ W_hh,
                                              const float* __restrict__ b_hh, u16* __restrict__ Hall){
  __shared__ u16 ha[2][16][72];   // [buf][seq][d], row 144 B (16B-aligned)
  const int tid = threadIdx.x;
  const int w = tid >> 6, lane = tid & 63;
  const int col = lane & 15, kq = lane >> 4;
  const int dir  = blockIdx.x >> 6;   // 0:right 1:down 2:left 3:up
  const int sblk = blockIdx.x & 63;
  const int doff = 16 * w + 4 * kq;   // this lane's 4 d values
  const int dq   = 4 * w + kq;

  // A-frags: W_hh rows g = g3*64 + 16w + col, standard k order, gate-scaled
  s8v afrag[3][2];
  #pragma unroll
  for (int g3 = 0; g3 < 3; g3++) {
    float sc = (g3 == 2) ? SC_N : SC_RZ;
    const float* wr = W_hh + (g3 * 64 + 16 * w + col) * 64;
    #pragma unroll
    for (int kc = 0; kc < 2; kc++) {
      s8v f;
      #pragma unroll
      for (int i = 0; i < 8; i++) f[i] = (short)f2bf(sc * wr[kc * 32 + kq * 8 + i]);
      afrag[g3][kc] = f;
    }
  }
  // n-gate hidden bias in accumulator init (r,z b_hh folded into G)
  f4v biasn;
  {
    const float* bb = b_hh + 128 + doff;
    biasn = (f4v){SC_N * bb[0], SC_N * bb[1], SC_N * bb[2], SC_N * bb[3]};
  }

  const int seq = sblk * 16 + col;             // 0..1023
  const int b = seq >> 7, a = seq & 127;
  long base; int stride;
  if ((dir & 1) == 0) { base = ((long)(b * 128 + a)) * 128; stride = 1;   } // scan over w
  else                { base = (long)b * 16384 + a;         stride = 128; } // scan over h
  const int rev = dir >> 1;
  const long pd = rev ? -(long)stride : (long)stride;
  u16* __restrict__ Hs = Hall + (long)dir * (NSp * 64);
  const long pos0 = base + (long)(rev ? 127 : 0) * stride;
  const u16* gq = G  + pos0 * 192 + dq * 12;   // 24B contiguous (r,z,n) triple
  u16*       hq = Hs + pos0 * 64  + doff;

  for (int i = tid; i < 2 * 16 * 72; i += 256) ((u16*)ha)[i] = 0;   // h0 = 0

  float hold[4] = {0.f, 0.f, 0.f, 0.f};

  // depth-2 G prefetch: t=0 and t=1 in flight before the loop
  uint2 xr0, xz0, xn0, xr1, xz1, xn1;
  xr0 = *(const uint2*)(gq); xz0 = *(const uint2*)(gq + 4); xn0 = *(const uint2*)(gq + 8);
  gq += pd * 192;
  xr1 = *(const uint2*)(gq); xz1 = *(const uint2*)(gq + 4); xn1 = *(const uint2*)(gq + 8);
  __syncthreads();   // one full drain, before the loop only

  int p = 0;
  for (int t = 0; t < 128; t++) {
    // issue prefetch for t+2 (~2 steps of latency slack)
    uint2 nxr, nxz, nxn;
    if (t < 126) {
      gq += pd * 192;
      nxr = *(const uint2*)(gq); nxz = *(const uint2*)(gq + 4); nxn = *(const uint2*)(gq + 8);
    }

    // B-frags (n=col=seq): two b128 reads, standard contiguous layout
    s8v u0 = *(const s8v*)(&ha[p][col][kq * 8]);
    s8v u1 = *(const s8v*)(&ha[p][col][32 + kq * 8]);

    f4v acc0 = (f4v){0.f, 0.f, 0.f, 0.f};
    f4v acc1 = (f4v){0.f, 0.f, 0.f, 0.f};
    f4v acc2 = biasn;
    acc0 = __builtin_amdgcn_mfma_f32_16x16x32_bf16(afrag[0][0], u0, acc0, 0, 0, 0);
    acc1 = __builtin_amdgcn_mfma_f32_16x16x32_bf16(afrag[1][0], u0, acc1, 0, 0, 0);
    acc2 = __builtin_amdgcn_mfma_f32_16x16x32_bf16(afrag[2][0], u0, acc2, 0, 0, 0);
    acc0 = __builtin_amdgcn_mfma_f32_16x16x32_bf16(afrag[0][1], u1, acc0, 0, 0, 0);
    acc1 = __builtin_amdgcn_mfma_f32_16x16x32_bf16(afrag[1][1], u1, acc1, 0, 0, 0);
    acc2 = __builtin_amdgcn_mfma_f32_16x16x32_bf16(afrag[2][1], u1, acc2, 0, 0, 0);

    // gate phase — lane-local (gates g3*64 + doff + r, seq = col)
    const u16* pxr = (const u16*)&xr0;
    const u16* pxz = (const u16*)&xz0;
    const u16* pxn = (const u16*)&xn0;
    float hh[4];
    #pragma unroll
    for (int r = 0; r < 4; r++) {
      float rr = rcpa(1.f + ex2f(bf2f(pxr[r]) + acc0[r]));
      float zz = rcpa(1.f + ex2f(bf2f(pxz[r]) + acc1[r]));
      float nn = 2.f * rcpa(1.f + ex2f(bf2f(pxn[r]) + rr * acc2[r])) - 1.f;
      float h  = nn + zz * (hold[r] - nn);
      hold[r] = h; hh[r] = h;
    }
    uint2 wv;
    wv.x = pk2bf(hh[0], hh[1]);
    wv.y = pk2bf(hh[2], hh[3]);
    *(uint2*)(&ha[p ^ 1][col][doff]) = wv;   // h for next step (other buffer)
    *(uint2*)(hq) = wv;                      // stream h out (never waited on)
    hq += pd * 64;

    // rotate prefetch pipeline
    xr0 = xr1; xz0 = xz1; xn0 = xn1;
    if (t < 126) { xr1 = nxr; xz1 = nxz; xn1 = nxn; }

    // raw barrier: drain LDS only; global loads/stores stay in flight
    asm volatile("s_waitcnt lgkmcnt(0)" ::: "memory");
    __builtin_amdgcn_s_barrier();
    __builtin_amdgcn_sched_barrier(0);
    p ^= 1;
  }
}

// ---------------------------------------------------------------------------
// Kernel 3: out[b,c,h,w] = bo[c] + Wo[c,:] . (sum_dirs h)/4   (fp32 out)
// Staging widened: 16B Hall loads per dir, cvt_pk repack, wide LDS writes.
// ---------------------------------------------------------------------------
__global__ __launch_bounds__(256) void k_out(const u16* __restrict__ Hall, const float* __restrict__ Wo,
                                             const float* __restrict__ bo, float* __restrict__ out){
  __shared__ u16 hs4[64][72];
  const int tid = threadIdx.x;
  const int wave = tid >> 6, lane = tid & 63;
  const int col = lane & 15, kq = lane >> 4;
  const long s0 = (long)blockIdx.x * 64;
  const int b   = (int)(s0 >> 14);
  const int hw0 = (int)(s0 & 16383);

  s8v bfrag[3][2]; f4v biasf[3];
  #pragma unroll
  for (int j = 0; j < 3; j++) {
    int g = wave * 48 + j * 16 + col;
    bfrag[j][0] = load8_f32_as_bf16(Wo + g * 64 + kq * 8);
    bfrag[j][1] = load8_f32_as_bf16(Wo + g * 64 + 32 + kq * 8);
    float bb = bo[g];
    biasf[j] = (f4v){bb, bb, bb, bb};
  }

  // Stage (sum of 4 direction h)/4 as bf16 — 16B loads per dir
  for (int idx = tid; idx < 64 * 8; idx += 256) {
    int sl = idx >> 3;
    int d8 = (idx & 7) * 8;
    long p = (s0 + sl) * 64 + d8;
    float s[8];
    {
      uint4 v = *(const uint4*)(Hall + p);
      const u16* pv = (const u16*)&v;
      #pragma unroll
      for (int i = 0; i < 8; i++) s[i] = bf2f(pv[i]);
    }
    #pragma unroll
    for (int dd = 1; dd < 4; dd++) {
      uint4 v = *(const uint4*)(Hall + dd * (NSp * 64) + p);
      const u16* pv = (const u16*)&v;
      #pragma unroll
      for (int i = 0; i < 8; i++) s[i] += bf2f(pv[i]);
    }
    uint2 w0, w1;
    w0.x = pk2bf(0.25f * s[0], 0.25f * s[1]);
    w0.y = pk2bf(0.25f * s[2], 0.25f * s[3]);
    w1.x = pk2bf(0.25f * s[4], 0.25f * s[5]);
    w1.y = pk2bf(0.25f * s[6], 0.25f * s[7]);
    *(uint2*)(&hs4[sl][d8]) = w0;
    *(uint2*)(&hs4[sl][d8 + 4]) = w1;
  }
  __syncthreads();

  f4v acc[4][3];
  #pragma unroll
  for (int m = 0; m < 4; m++)
    #pragma unroll
    for (int j = 0; j < 3; j++) acc[m][j] = biasf[j];

  #pragma unroll
  for (int kc = 0; kc < 2; kc++) {
    #pragma unroll
    for (int m = 0; m < 4; m++) {
      s8v a = *(const s8v*)(&hs4[m * 16 + col][kc * 32 + kq * 8]);
      #pragma unroll
      for (int j = 0; j < 3; j++)
        acc[m][j] = __builtin_amdgcn_mfma_f32_16x16x32_bf16(a, bfrag[j][kc], acc[m][j], 0, 0, 0);
    }
  }

  #pragma unroll
  for (int j = 0; j < 3; j++) {
    int g = wave * 48 + j * 16 + col;
    #pragma unroll
    for (int m = 0; m < 4; m++) {
      float4 v;
      v.x = acc[m][j][0]; v.y = acc[m][j][1];
      v.z = acc[m][j][2]; v.w = acc[m][j][3];
      long addr = ((long)(b * 192 + g) << 14) + hw0 + m * 16 + kq * 4;
      *(float4*)(out + addr) = v;
    }
  }
}

// ---------------------------------------------------------------------------
extern "C" void kernel_launch(void* const* d_in, const int* in_sizes, int n_in,
                              void* d_out, int out_size, void* d_ws, size_t ws_size,
                              hipStream_t stream){
  const float* x    = (const float*)d_in[0];
  const float* Wi   = (const float*)d_in[1];
  const float* bi   = (const float*)d_in[2];
  const float* W_ih = (const float*)d_in[3];
  const float* W_hh = (const float*)d_in[4];
  const float* b_ih = (const float*)d_in[5];
  const float* b_hh = (const float*)d_in[6];
  const float* Wo   = (const float*)d_in[7];
  const float* bo   = (const float*)d_in[8];

  char* ws = (char*)d_ws;
  u16*   wcomb = (u16*)(ws);                       // 192*192 bf16        = 73728 B
  float* bcomb = (float*)(ws + 73728);             // 192 fp32            = 768 B
  u16*   G     = (u16*)(ws + 74496);               // 131072*192 bf16     = 50331648 B
  u16*   Hall  = (u16*)(ws + 50406144);            // 4*131072*64 bf16    = 67108864 B
                                                   // total               = 117515008 B

  k_wcomb<<<145,  256, 0, stream>>>(Wi, bi, W_ih, b_ih, b_hh, wcomb, bcomb);
  k_gates<<<2048, 256, 0, stream>>>(x, wcomb, bcomb, G);
  k_scan <<<256,  256, 0, stream>>>(G, W_hh, b_hh, Hall);
  k_out  <<<2048, 256, 0, stream>>>(Hall, Wo, bo, (float*)d_out);
}